// Round 3
// baseline (260.156 us; speedup 1.0000x reference)
//
#include <hip/hip_runtime.h>
#include <hip/hip_bf16.h>

typedef __attribute__((ext_vector_type(8))) short short8;
typedef __attribute__((ext_vector_type(4))) float f32x4;

#define B_T 200
#define B_D 128

static __device__ __forceinline__ short f2bf(float f) {
  // round-to-nearest-even f32 -> bf16 (inputs are finite)
  unsigned u = __builtin_bit_cast(unsigned, f);
  u += 0x7fffu + ((u >> 16) & 1u);
  return (short)(u >> 16);
}
static __device__ __forceinline__ float bf2f(short s) {
  unsigned u = ((unsigned)(unsigned short)s) << 16;
  return __builtin_bit_cast(float, u);
}
static __device__ __forceinline__ short8 cvt8(f32x4 a, f32x4 b) {
  short8 t;
  t[0] = f2bf(a[0]); t[1] = f2bf(a[1]); t[2] = f2bf(a[2]); t[3] = f2bf(a[3]);
  t[4] = f2bf(b[0]); t[5] = f2bf(b[1]); t[6] = f2bf(b[2]); t[7] = f2bf(b[3]);
  return t;
}

__global__ __launch_bounds__(512, 4)
void ta_fused(const float* __restrict__ x,      // [B,T,D]
              const float* __restrict__ cand,   // [B,D]
              const void*  __restrict__ maskp,  // [B,T] int32 or 1-byte bool
              const float* __restrict__ W1,     // [384,128]
              const float* __restrict__ b1,     // [128]
              const float* __restrict__ ap,     // [1]
              const float* __restrict__ W2,     // [128]
              const float* __restrict__ b2p,    // [1]
              float* __restrict__ out)          // [B,D]
{
  // wbt fragment-linear bf16: element (k,j) at ((k>>3)*128 + j)*8 + (k&7).
  __shared__ __align__(16) short wbt[B_D * B_D];
  __shared__ float part[4][B_D];   // beta partials (b1 folded into part[0])
  __shared__ float w2_lds[B_D];
  __shared__ float pout[8][B_D];
  __shared__ float scores[208];
  __shared__ float red[16];

  const int b    = blockIdx.x;
  const int tid  = threadIdx.x;
  const int lane = tid & 63;
  const int wv   = tid >> 6;      // 0..7
  const int l15  = lane & 15;
  const int g    = lane >> 4;     // 0..3

  // ---- issue the full x stream FIRST (overlaps everything up to the converts)
  const int row0 = wv * 16 + l15;                         // <= 127 < 200
  int row1 = (8 + wv) * 16 + l15; if (row1 > B_T - 1) row1 = B_T - 1;
  const float* xr0 = x + ((size_t)b * B_T + row0) * B_D + g * 8;
  const float* xr1 = x + ((size_t)b * B_T + row1) * B_D + g * 8;
  f32x4 r00 = *(const f32x4*)(xr0 +  0), r01 = *(const f32x4*)(xr0 +  4);
  f32x4 r02 = *(const f32x4*)(xr0 + 32), r03 = *(const f32x4*)(xr0 + 36);
  f32x4 r04 = *(const f32x4*)(xr0 + 64), r05 = *(const f32x4*)(xr0 + 68);
  f32x4 r06 = *(const f32x4*)(xr0 + 96), r07 = *(const f32x4*)(xr0 + 100);
  f32x4 r10 = *(const f32x4*)(xr1 +  0), r11 = *(const f32x4*)(xr1 +  4);
  f32x4 r12 = *(const f32x4*)(xr1 + 32), r13 = *(const f32x4*)(xr1 + 36);
  f32x4 r14 = *(const f32x4*)(xr1 + 64), r15 = *(const f32x4*)(xr1 + 68);
  f32x4 r16 = *(const f32x4*)(xr1 + 96), r17 = *(const f32x4*)(xr1 + 100);

  // ---- mask dtype probe: every wave scans the SAME 512 B -> block-consistent,
  // no LDS, no barrier. int32 storage has all off-aligned bytes == 0.
  int flag1b;
  {
    const unsigned char* mb = (const unsigned char*)maskp;
    unsigned long long v8 = *(const unsigned long long*)(mb + lane * 8);
    flag1b = __any((v8 & 0xFFFFFF00FFFFFF00ull) != 0ull);
  }
  // hoist this block's mask row (off the softmax critical path)
  bool mk = false;
  if (tid < B_T) {
    if (flag1b) mk = ((const unsigned char*)maskp)[(size_t)b * B_T + tid] != 0;
    else        mk = ((const int*)maskp)[(size_t)b * B_T + tid] != 0;
  }

  if (tid < B_D) w2_lds[tid] = W2[tid];

  // ---- phase 1: Wb = W1a + c (*) W1c -> wbt ; beta partials -> part
  const float* cb = cand + (size_t)b * B_D;
  {
    const int j  = tid & 127;       // fixed per thread (512 % 128 == 0)
    const int q  = tid >> 7;        // 0..3
    #pragma unroll 4
    for (int it = 0; it < 16; ++it) {
      int k0 = it * 8 + q * 2;
      float c0 = cb[k0], c1 = cb[k0 + 1];
      float wa0 = W1[(size_t)k0 * B_D + j];
      float wc0 = W1[(size_t)(256 + k0) * B_D + j];
      float wa1 = W1[(size_t)(k0 + 1) * B_D + j];
      float wc1 = W1[(size_t)(256 + k0 + 1) * B_D + j];
      unsigned lo = (unsigned short)f2bf(wa0 + c0 * wc0);
      unsigned hi = (unsigned short)f2bf(wa1 + c1 * wc1);
      ((unsigned*)wbt)[((k0 >> 3) * B_D + j) * 4 + ((k0 & 7) >> 1)] = lo | (hi << 16);
    }
    // part[q][j] = (q==0 ? b1[j] : 0) + sum_{k in q-slice} c[k]*W1b[k][j]
    float s = (q == 0) ? b1[j] : 0.f;
    const float* w1b = W1 + (size_t)(B_D + q * 32) * B_D + j;
    #pragma unroll 4
    for (int k = 0; k < 32; ++k) s += cb[q * 32 + k] * w1b[(size_t)k * B_D];
    part[q][j] = s;
  }
  __syncthreads();   // the ONLY barrier before MFMA

  float betaL[8], w2L[8];
  #pragma unroll
  for (int nt = 0; nt < 8; ++nt) {
    int col = nt * 16 + l15;
    betaL[nt] = part[0][col] + part[1][col] + part[2][col] + part[3][col];
    w2L[nt]   = w2_lds[col];
  }
  const float alpha = ap[0];
  const float b2    = b2p[0];

  // ---- convert x -> A fragments (x latency already hidden under phase 1)
  short8 af00 = cvt8(r00, r01), af01 = cvt8(r02, r03);
  short8 af02 = cvt8(r04, r05), af03 = cvt8(r06, r07);
  short8 af10 = cvt8(r10, r11), af11 = cvt8(r12, r13);
  short8 af12 = cvt8(r14, r15), af13 = cvt8(r16, r17);

  // ---- phase 2: per-tile MFMA + fused PReLU + W2 epilogue -> scores
#define TILE_SCORE(A0, A1, A2, A3, TB) do {                                   \
    float sc[4] = {0.f, 0.f, 0.f, 0.f};                                       \
    _Pragma("unroll")                                                         \
    for (int nt = 0; nt < 8; ++nt) {                                          \
      f32x4 acc = {0.f, 0.f, 0.f, 0.f};                                       \
      const short8* wp = (const short8*)wbt + g * B_D + nt * 16 + l15;        \
      acc = __builtin_amdgcn_mfma_f32_16x16x32_bf16(A0, wp[0],    acc, 0,0,0);\
      acc = __builtin_amdgcn_mfma_f32_16x16x32_bf16(A1, wp[512],  acc, 0,0,0);\
      acc = __builtin_amdgcn_mfma_f32_16x16x32_bf16(A2, wp[1024], acc, 0,0,0);\
      acc = __builtin_amdgcn_mfma_f32_16x16x32_bf16(A3, wp[1536], acc, 0,0,0);\
      _Pragma("unroll")                                                       \
      for (int r = 0; r < 4; ++r) {                                           \
        float h = acc[r] + betaL[nt];                                         \
        float p = (h >= 0.f) ? h : alpha * h;                                 \
        sc[r] += p * w2L[nt];                                                 \
      }                                                                       \
    }                                                                         \
    _Pragma("unroll")                                                         \
    for (int r = 0; r < 4; ++r) {                                             \
      float v = sc[r];                                                        \
      v += __shfl_xor(v, 1, 16); v += __shfl_xor(v, 2, 16);                   \
      v += __shfl_xor(v, 4, 16); v += __shfl_xor(v, 8, 16);                   \
      if (l15 == 0) scores[(TB) + g * 4 + r] = v + b2;                        \
    }                                                                         \
  } while (0)

  const int ntile = (wv < 5) ? 2 : 1;
  TILE_SCORE(af00, af01, af02, af03, wv * 16);
  if (ntile > 1) TILE_SCORE(af10, af11, af12, af13, (8 + wv) * 16);
  __syncthreads();

  // ---- phase 3: masked softmax over t
  {
    float s = (tid < B_T && mk) ? scores[tid] : -INFINITY;
    float v = s;
    #pragma unroll
    for (int m = 32; m >= 1; m >>= 1) v = fmaxf(v, __shfl_xor(v, m, 64));
    if (lane == 0) red[wv] = v;
    __syncthreads();
    float mx = -INFINITY;
    #pragma unroll
    for (int i = 0; i < 8; ++i) mx = fmaxf(mx, red[i]);
    float e = mk ? __expf(s - mx) : 0.f;
    float sv = e;
    #pragma unroll
    for (int m = 32; m >= 1; m >>= 1) sv += __shfl_xor(sv, m, 64);
    if (lane == 0) red[8 + wv] = sv;
    __syncthreads();
    float Z = 0.f;
    #pragma unroll
    for (int i = 0; i < 8; ++i) Z += red[8 + i];
    if (tid < 208) scores[tid] = e / Z;    // tid in [200,208): e==0 -> 0
  }
  __syncthreads();

  // ---- phase 4: out[b,:] = sum_t w[t]*x[t,:] from held A fragments
  {
    float w0 = scores[wv * 16 + l15];
    float w1 = (ntile > 1) ? scores[(8 + wv) * 16 + l15] : 0.f;
    #pragma unroll
    for (int ks = 0; ks < 4; ++ks) {
      short8 t0 = (ks == 0) ? af00 : (ks == 1) ? af01 : (ks == 2) ? af02 : af03;
      short8 t1 = (ks == 0) ? af10 : (ks == 1) ? af11 : (ks == 2) ? af12 : af13;
      float accw[8];
      #pragma unroll
      for (int e = 0; e < 8; ++e) accw[e] = w0 * bf2f(t0[e]) + w1 * bf2f(t1[e]);
      #pragma unroll
      for (int e = 0; e < 8; ++e) {
        float v = accw[e];
        v += __shfl_xor(v, 1, 16); v += __shfl_xor(v, 2, 16);
        v += __shfl_xor(v, 4, 16); v += __shfl_xor(v, 8, 16);
        if (l15 == 0) pout[wv][ks * 32 + g * 8 + e] = v;
      }
    }
  }
  __syncthreads();
  if (tid < B_D) {
    float s = 0.f;
    #pragma unroll
    for (int i = 0; i < 8; ++i) s += pout[i][tid];
    out[(size_t)b * B_D + tid] = s;
  }
}

extern "C" void kernel_launch(void* const* d_in, const int* in_sizes, int n_in,
                              void* d_out, int out_size, void* d_ws, size_t ws_size,
                              hipStream_t stream) {
  const float* x    = (const float*)d_in[0];
  const float* cand = (const float*)d_in[1];
  const void*  mask = d_in[2];
  const float* W1   = (const float*)d_in[3];
  const float* b1   = (const float*)d_in[4];
  const float* a    = (const float*)d_in[5];
  const float* W2   = (const float*)d_in[6];
  const float* b2   = (const float*)d_in[7];
  float* out = (float*)d_out;
  const int B = in_sizes[1] / B_D;   // candidate is [B,128]
  ta_fused<<<B, 512, 0, stream>>>(x, cand, mask, W1, b1, a, W2, b2, out);
}